// Round 6
// baseline (1709.928 us; speedup 1.0000x reference)
//
#include <hip/hip_runtime.h>
#include <hip/hip_bf16.h>
#include <math.h>

// Problem constants
constexpr int Bn   = 32;
constexpr int Sn   = 256;
constexpr int Dn   = 512;
constexpr int Hn   = 8;
constexpr int DKn  = 64;
constexpr int Fn   = 2048;
constexpr int Ln   = 6;
constexpr int FEATn= 9;
constexpr int BSn  = Bn * Sn;          // 8192 rows

typedef __hip_bfloat16 bf16;
typedef __attribute__((ext_vector_type(8))) short short8;
typedef __attribute__((ext_vector_type(4))) short short4v;
typedef __attribute__((ext_vector_type(4))) float f32x4;

// global->LDS async copy, 16B per lane, LDS dest = wave-uniform base + lane*16
#define GLOAD_LDS16(gp, lp)                                                   \
    __builtin_amdgcn_global_load_lds(                                         \
        (const __attribute__((address_space(1))) void*)(gp),                  \
        (__attribute__((address_space(3))) void*)(lp), 16, 0, 0)

__device__ __forceinline__ short f2bs(float f) {
    __hip_bfloat16 h = __float2bfloat16(f);
    return *reinterpret_cast<short*>(&h);
}
__device__ __forceinline__ float bs2f(short s) {
    unsigned u = ((unsigned)(unsigned short)s) << 16;
    return *reinterpret_cast<float*>(&u);
}

// ---------------------------------------------------------------------------
// Embedding: x = (tgt*mask)@w_f2h + b_f2h + pos_emb + emb_time/gender/race
// ---------------------------------------------------------------------------
__global__ __launch_bounds__(256)
void k_embed(const float* __restrict__ tgt, const float* __restrict__ mask,
             const float* __restrict__ w_f2h, const float* __restrict__ b_f2h,
             const int* __restrict__ timei, const int* __restrict__ gender,
             const int* __restrict__ race,
             const float* __restrict__ emb_t, const float* __restrict__ emb_g,
             const float* __restrict__ emb_r, bf16* __restrict__ x)
{
    int idx = blockIdx.x * 256 + threadIdx.x;   // over BSn*Dn
    int d  = idx & (Dn - 1);
    int bs = idx >> 9;                           // /Dn
    int b  = bs / Sn;
    int s  = bs & (Sn - 1);
    const float* tg = tgt  + (size_t)bs * FEATn;
    const float* mk = mask + (size_t)bs * FEATn;
    float acc = b_f2h[d];
    #pragma unroll
    for (int f = 0; f < FEATn; ++f) acc += tg[f] * mk[f] * w_f2h[f * Dn + d];
    float phase = (float)s * expf(-((float)d / (float)Dn) * 9.210340372f); // ln(1e4)
    acc += (d & 1) ? cosf(phase) : sinf(phase);
    acc += emb_t[(size_t)timei[bs] * Dn + d];
    acc += emb_g[(size_t)gender[b] * Dn + d];
    acc += emb_r[(size_t)race[b]   * Dn + d];
    x[idx] = __float2bfloat16(acc);
}

// ---------------------------------------------------------------------------
// fp32 -> bf16 elementwise convert
// ---------------------------------------------------------------------------
__global__ __launch_bounds__(256)
void k_cvt(const float* __restrict__ in, bf16* __restrict__ out)
{
    int i = blockIdx.x * 256 + threadIdx.x;
    out[i] = __float2bfloat16(in[i]);
}

// ---------------------------------------------------------------------------
// Transpose + convert: in fp32 [B][R][C] -> out bf16 [B][C][R]
// Batched over up to 6 source/dest pairs: z in [0, 6*ZB); sel = z / ZB.
// ---------------------------------------------------------------------------
__global__ __launch_bounds__(256)
void k_tcvt6(const float* __restrict__ i0, bf16* __restrict__ o0,
             const float* __restrict__ i1, bf16* __restrict__ o1,
             const float* __restrict__ i2, bf16* __restrict__ o2,
             const float* __restrict__ i3, bf16* __restrict__ o3,
             const float* __restrict__ i4, bf16* __restrict__ o4,
             const float* __restrict__ i5, bf16* __restrict__ o5,
             int R, int C, int ZB)
{
    __shared__ float ts[32][33];
    const int sel = blockIdx.z / ZB, zi = blockIdx.z % ZB;
    const float* in  = sel == 0 ? i0 : sel == 1 ? i1 : sel == 2 ? i2
                     : sel == 3 ? i3 : sel == 4 ? i4 : i5;
    bf16*        out = sel == 0 ? o0 : sel == 1 ? o1 : sel == 2 ? o2
                     : sel == 3 ? o3 : sel == 4 ? o4 : o5;
    const int t  = threadIdx.x;
    const int tx = t & 31, ty = t >> 5;       // 8 rows per pass
    const int r0 = blockIdx.y * 32, c0 = blockIdx.x * 32;
    const size_t zo = (size_t)zi * R * C;
    #pragma unroll
    for (int i = 0; i < 4; ++i)
        ts[ty + 8 * i][tx] = in[zo + (size_t)(r0 + ty + 8 * i) * C + c0 + tx];
    __syncthreads();
    #pragma unroll
    for (int i = 0; i < 4; ++i)
        out[zo + (size_t)(c0 + ty + 8 * i) * R + r0 + tx] =
            __float2bfloat16(ts[tx][ty + 8 * i]);
}

// ---------------------------------------------------------------------------
// Prep for k_final2: Wcat bf16 [32][512] = concat(w_out^T, w_m^T, zero-pad),
// bcat fp32 [32] = concat(b_out, b_m, 0)
// ---------------------------------------------------------------------------
__global__ __launch_bounds__(256)
void k_prep_final(const float* __restrict__ w_out, const float* __restrict__ b_out,
                  const float* __restrict__ w_m, const float* __restrict__ b_m,
                  bf16* __restrict__ Wcat, float* __restrict__ bcat)
{
    int idx = blockIdx.x * 256 + threadIdx.x;   // 32*512
    int n = idx >> 9, k = idx & 511;
    float v = 0.f;
    if (n < FEATn)          v = w_out[(size_t)k * FEATn + n];
    else if (n < 2 * FEATn) v = w_m[(size_t)k * FEATn + (n - FEATn)];
    Wcat[idx] = __float2bfloat16(v);
    if (idx < 32) {
        float bv = idx < FEATn ? b_out[idx]
                 : (idx < 2 * FEATn ? b_m[idx - FEATn] : 0.f);
        bcat[idx] = bv;
    }
}

// ---------------------------------------------------------------------------
// bf16 MFMA GEMM: C[M,N] = A[M,K] @ Bt[N,K]^T + bias (+R)(ReLU)
// Tile BM x BN (BM==BN), BK=32, 4 waves 2x2, wave (BM/2)x(BN/2).
// blockIdx.z picks (A,W,bias,C).  TRANSV && z==2: operand-swapped MFMA ->
// writes C^T as [N][M] (for attention V).
// Epilogue: acc -> bf16 -> padded LDS tile -> coalesced b128 global stores
// (scalar 2B stores were the round-5 bottleneck: 64 VMEM ops/thread with only
// 16 K-iters to amortize them; now 8 b128 ops/thread).
// ---------------------------------------------------------------------------
template<int BM, int BN, bool RELU, bool RESID, bool TRANSV = false>
__global__ __launch_bounds__(256)
void k_gemm_bf(const bf16* __restrict__ A0, const bf16* __restrict__ A1,
               const bf16* __restrict__ A2,
               const bf16* __restrict__ W0, const bf16* __restrict__ W1,
               const bf16* __restrict__ W2,
               const float* __restrict__ bi0, const float* __restrict__ bi1,
               const float* __restrict__ bi2,
               const bf16* __restrict__ R,
               bf16* __restrict__ C0, bf16* __restrict__ C1, bf16* __restrict__ C2,
               int M, int N, int K)
{
    constexpr int WTM = BM / 2, WTN = BN / 2;     // wave tile
    constexpr int MT  = WTM / 16, NT = WTN / 16;  // MFMA tiles per wave
    constexpr int NCA = BM / 64;                  // A staging calls per wave
    constexpr int NCB = BN / 64;
    constexpr int CSTR   = BN + 8;                // Cs row stride (shorts)
    constexpr int PASSES = BM / 64;               // epilogue row-half passes

    const int z = blockIdx.z;
    const short* A   = (const short*)(z == 0 ? A0 : (z == 1 ? A1 : A2));
    const short* W   = (const short*)(z == 0 ? W0 : (z == 1 ? W1 : W2));
    const float* bia = (z == 0 ? bi0 : (z == 1 ? bi1 : bi2));
    bf16*        C   = (z == 0 ? C0 : (z == 1 ? C1 : C2));

    __shared__ __align__(16) short As[BM * 32];   // [row][k] 64B rows
    __shared__ __align__(16) short Bs[BN * 32];
    __shared__ __align__(16) short Cs[64 * CSTR]; // epilogue staging

    const int t    = threadIdx.x;
    const int w    = t >> 6, lane = t & 63;
    const int m0   = blockIdx.y * BM, n0 = blockIdx.x * BN;
    const int l16  = lane & 15, quad = lane >> 4;
    const int wm   = (w & 1) * WTM, wn = (w >> 1) * WTN;

    const short* Agp[NCA];
    const short* Bgp[NCB];
    #pragma unroll
    for (int i = 0; i < NCA; ++i) {
        const int c = w * BM + i * 64 + lane;
        Agp[i] = A + (size_t)(m0 + (c >> 2)) * K + (c & 3) * 8;
    }
    #pragma unroll
    for (int i = 0; i < NCB; ++i) {
        const int c = w * BN + i * 64 + lane;
        Bgp[i] = W + (size_t)(n0 + (c >> 2)) * K + (c & 3) * 8;
    }

    f32x4 acc[MT][NT] = {};
    const bool tv = TRANSV && (z == 2);

    for (int k0 = 0; k0 < K; k0 += 32) {
        #pragma unroll
        for (int i = 0; i < NCA; ++i) {
            GLOAD_LDS16(Agp[i], As + (w * BM + i * 64) * 8);
            Agp[i] += 32;
        }
        #pragma unroll
        for (int i = 0; i < NCB; ++i) {
            GLOAD_LDS16(Bgp[i], Bs + (w * BN + i * 64) * 8);
            Bgp[i] += 32;
        }
        __syncthreads();

        short8 af[MT], bf[NT];
        #pragma unroll
        for (int mi = 0; mi < MT; ++mi)
            af[mi] = *(const short8*)(As + (wm + mi * 16 + l16) * 32 + quad * 8);
        #pragma unroll
        for (int ni = 0; ni < NT; ++ni)
            bf[ni] = *(const short8*)(Bs + (wn + ni * 16 + l16) * 32 + quad * 8);
        if (tv) {
            #pragma unroll
            for (int mi = 0; mi < MT; ++mi)
                #pragma unroll
                for (int ni = 0; ni < NT; ++ni)
                    acc[mi][ni] = __builtin_amdgcn_mfma_f32_16x16x32_bf16(
                        bf[ni], af[mi], acc[mi][ni], 0, 0, 0);
        } else {
            #pragma unroll
            for (int mi = 0; mi < MT; ++mi)
                #pragma unroll
                for (int ni = 0; ni < NT; ++ni)
                    acc[mi][ni] = __builtin_amdgcn_mfma_f32_16x16x32_bf16(
                        af[mi], bf[ni], acc[mi][ni], 0, 0, 0);
        }
        __syncthreads();
    }

    if (tv) {
        // D[m = W-row (wn side)][n = token (wm side)]; output C^T [N][M].
        constexpr int CPR = BM / 8;
        #pragma unroll
        for (int p = 0; p < PASSES; ++p) {
            if (PASSES == 1 || wn == p * 64) {
                #pragma unroll
                for (int ni = 0; ni < NT; ++ni) {
                    #pragma unroll
                    for (int r = 0; r < 4; ++r) {
                        const int lrow = wn - p * 64 + ni * 16 + quad * 4 + r;
                        const float bb = bia[n0 + p * 64 + lrow];
                        #pragma unroll
                        for (int mi = 0; mi < MT; ++mi)
                            Cs[lrow * CSTR + wm + mi * 16 + l16] =
                                f2bs(acc[mi][ni][r] + bb);
                    }
                }
            }
            __syncthreads();
            #pragma unroll
            for (int c = 0; c < 64 * CPR; c += 256) {
                const int row = (c + t) / CPR, colc = (c + t) % CPR;
                short8 cv = *(const short8*)(Cs + row * CSTR + colc * 8);
                *(short8*)((short*)C + (size_t)(n0 + p * 64 + row) * M
                                      + m0 + colc * 8) = cv;
            }
            __syncthreads();
        }
    } else {
        constexpr int CPR = BN / 8;
        #pragma unroll
        for (int p = 0; p < PASSES; ++p) {
            if (PASSES == 1 || wm == p * 64) {
                #pragma unroll
                for (int ni = 0; ni < NT; ++ni) {
                    const float bb = bia[n0 + wn + ni * 16 + l16];
                    #pragma unroll
                    for (int mi = 0; mi < MT; ++mi) {
                        const int lrow0 = wm - p * 64 + mi * 16 + quad * 4;
                        #pragma unroll
                        for (int r = 0; r < 4; ++r) {
                            float v = acc[mi][ni][r] + bb;
                            if (RELU) v = fmaxf(v, 0.f);
                            Cs[(lrow0 + r) * CSTR + wn + ni * 16 + l16] = f2bs(v);
                        }
                    }
                }
            }
            __syncthreads();
            #pragma unroll
            for (int c = 0; c < 64 * CPR; c += 256) {
                const int row = (c + t) / CPR, colc = (c + t) % CPR;
                const size_t goff = (size_t)(m0 + p * 64 + row) * N + n0 + colc * 8;
                short8 cv = *(const short8*)(Cs + row * CSTR + colc * 8);
                if (RESID) {
                    short8 rv = *(const short8*)((const short*)R + goff);
                    short8 ov;
                    #pragma unroll
                    for (int i = 0; i < 8; ++i)
                        ov[i] = f2bs(bs2f(cv[i]) + bs2f(rv[i]));
                    *(short8*)((short*)C + goff) = ov;
                } else {
                    *(short8*)((short*)C + goff) = cv;
                }
            }
            __syncthreads();
        }
    }
}

// ---------------------------------------------------------------------------
// MFMA attention. q,k in [B,S,H*DK]; vT in [H*DK][B*S]; out in [B,S,H*DK].
// Block = (b,h,64-query tile), 4 waves x (16q x 256k).
// ---------------------------------------------------------------------------
__global__ __launch_bounds__(256)
void k_attn_mfma(const bf16* __restrict__ q, const bf16* __restrict__ k,
                 const bf16* __restrict__ vT, bf16* __restrict__ ocat)
{
    __shared__ __align__(16) short smem[33280];      // 66560 B
    short* Vst = smem;            // [64 dv][256 key], 16B chunks XOR-swizzled
    short* Ks  = smem + 16384;    // [256 key][64 dk], 16B chunks XOR-swizzled
    short* Ps  = smem + 16384;    // [64 q][264] bf16, overlays Ks (after barrier)
    short* Cs  = smem + 16384;    // [64 q][72] epilogue staging (after barrier)

    const int t = threadIdx.x, w = t >> 6, lane = t & 63;
    const int l16 = lane & 15, quad = lane >> 4;
    const int qt = blockIdx.x & 3;
    const int h  = (blockIdx.x >> 2) & 7;
    const int b  = blockIdx.x >> 5;
    const int q0 = qt * 64;

    const short* kg = (const short*)k  + (size_t)b * Sn * Dn + h * DKn;
    const short* qg = (const short*)q  + (size_t)b * Sn * Dn + h * DKn;
    const short* vg = (const short*)vT + (size_t)h * DKn * BSn + b * Sn;

    #pragma unroll
    for (int i = 0; i < 8; ++i) {
        const int c   = w * 512 + i * 64 + lane;
        const int key = c >> 3, cgk = (c & 7) ^ (key & 7);
        GLOAD_LDS16(kg + (size_t)key * Dn + cgk * 8, Ks + (w * 512 + i * 64) * 8);
        const int dv = c >> 5, cgv = (c & 31) ^ (dv & 7);
        GLOAD_LDS16(vg + (size_t)dv * BSn + cgv * 8, Vst + (w * 512 + i * 64) * 8);
    }

    const short* qp = qg + (size_t)(q0 + w * 16 + l16) * Dn + quad * 8;
    short8 bq0 = *(const short8*)(qp);
    short8 bq1 = *(const short8*)(qp + 32);
    __syncthreads();

    // ---- S^T = K @ Q^T ----
    f32x4 accs[16];
    #pragma unroll
    for (int mi = 0; mi < 16; ++mi) accs[mi] = f32x4{0.f, 0.f, 0.f, 0.f};
    #pragma unroll
    for (int mi = 0; mi < 16; ++mi) {
        const int key = mi * 16 + l16;
        const int r0s = (quad     ^ (key & 7)) * 8;
        const int r1s = ((quad+4) ^ (key & 7)) * 8;
        short8 af0 = *(const short8*)(Ks + key * 64 + r0s);
        short8 af1 = *(const short8*)(Ks + key * 64 + r1s);
        accs[mi] = __builtin_amdgcn_mfma_f32_16x16x32_bf16(af0, bq0, accs[mi], 0, 0, 0);
        accs[mi] = __builtin_amdgcn_mfma_f32_16x16x32_bf16(af1, bq1, accs[mi], 0, 0, 0);
    }

    // ---- softmax over keys ----
    float mx = -1e30f;
    #pragma unroll
    for (int mi = 0; mi < 16; ++mi)
        #pragma unroll
        for (int r = 0; r < 4; ++r) mx = fmaxf(mx, accs[mi][r]);
    mx = fmaxf(mx, __shfl_xor(mx, 16));
    mx = fmaxf(mx, __shfl_xor(mx, 32));
    float sum = 0.f;
    #pragma unroll
    for (int mi = 0; mi < 16; ++mi)
        #pragma unroll
        for (int r = 0; r < 4; ++r) {
            float e = __expf((accs[mi][r] - mx) * 0.125f);
            accs[mi][r] = e;
            sum += e;
        }
    sum += __shfl_xor(sum, 16);
    sum += __shfl_xor(sum, 32);
    const float rs = 1.f / sum;

    __syncthreads();

    short* pr = Ps + (w * 16 + l16) * 264;
    #pragma unroll
    for (int mi = 0; mi < 16; ++mi) {
        short4v pk;
        pk.x = f2bs(accs[mi][0] * rs);
        pk.y = f2bs(accs[mi][1] * rs);
        pk.z = f2bs(accs[mi][2] * rs);
        pk.w = f2bs(accs[mi][3] * rs);
        *(short4v*)(pr + mi * 16 + quad * 4) = pk;
    }
    __syncthreads();

    // ---- O = P @ V ----
    f32x4 acco[4];
    #pragma unroll
    for (int nt = 0; nt < 4; ++nt) acco[nt] = f32x4{0.f, 0.f, 0.f, 0.f};
    #pragma unroll
    for (int k0 = 0; k0 < 8; ++k0) {
        short8 pa = *(const short8*)(pr + k0 * 32 + quad * 8);
        #pragma unroll
        for (int nt = 0; nt < 4; ++nt) {
            const int dv = nt * 16 + l16;
            const int sl = ((4 * k0 + quad) ^ (dv & 7)) * 8;
            short8 vb = *(const short8*)(Vst + dv * 256 + sl);
            acco[nt] = __builtin_amdgcn_mfma_f32_16x16x32_bf16(pa, vb, acco[nt], 0, 0, 0);
        }
    }
    __syncthreads();   // P reads done before Cs overlays Ps

    // ---- epilogue via LDS -> coalesced b128 stores ----
    #pragma unroll
    for (int nt = 0; nt < 4; ++nt)
        #pragma unroll
        for (int r = 0; r < 4; ++r)
            Cs[(w * 16 + quad * 4 + r) * 72 + nt * 16 + l16] = f2bs(acco[nt][r]);
    __syncthreads();
    #pragma unroll
    for (int c = 0; c < 512; c += 256) {
        const int row = (c + t) >> 3, colc = (c + t) & 7;
        short8 cv = *(const short8*)(Cs + row * 72 + colc * 8);
        *(short8*)((short*)ocat + (size_t)(b * Sn + q0 + row) * Dn
                                 + h * DKn + colc * 8) = cv;
    }
}

// ---------------------------------------------------------------------------
// LayerNorm over D=512: one wave per row, b128 loads, shfl-only reduction.
// ---------------------------------------------------------------------------
__global__ __launch_bounds__(256)
void k_ln(const bf16* __restrict__ y, const float* __restrict__ g,
          const float* __restrict__ be, bf16* __restrict__ xo)
{
    const int t = threadIdx.x, w = t >> 6, lane = t & 63;
    const int row = blockIdx.x * 4 + w;
    const short* yr = (const short*)y + (size_t)row * Dn + lane * 8;
    short8 v8 = *(const short8*)yr;
    float f[8];
    float s1 = 0.f, s2 = 0.f;
    #pragma unroll
    for (int i = 0; i < 8; ++i) {
        f[i] = bs2f(v8[i]);
        s1 += f[i];
        s2 += f[i] * f[i];
    }
    #pragma unroll
    for (int off = 1; off < 64; off <<= 1) {
        s1 += __shfl_xor(s1, off);
        s2 += __shfl_xor(s2, off);
    }
    const float mean = s1 * (1.f / Dn);
    const float var  = s2 * (1.f / Dn) - mean * mean;
    const float isd  = rsqrtf(var + 1e-5f);
    const float4 g0 = *(const float4*)(g  + lane * 8);
    const float4 g1 = *(const float4*)(g  + lane * 8 + 4);
    const float4 b0 = *(const float4*)(be + lane * 8);
    const float4 b1 = *(const float4*)(be + lane * 8 + 4);
    const float gg[8] = {g0.x, g0.y, g0.z, g0.w, g1.x, g1.y, g1.z, g1.w};
    const float bb[8] = {b0.x, b0.y, b0.z, b0.w, b1.x, b1.y, b1.z, b1.w};
    short8 o8;
    #pragma unroll
    for (int i = 0; i < 8; ++i)
        o8[i] = f2bs((f[i] - mean) * isd * gg[i] + bb[i]);
    *(short8*)((short*)xo + (size_t)row * Dn + lane * 8) = o8;
}

// ---------------------------------------------------------------------------
// Final head as skinny MFMA GEMM: out = sigmoid(X @ Wcat^T + bcat).
// ---------------------------------------------------------------------------
__global__ __launch_bounds__(256)
void k_final2(const bf16* __restrict__ x, const bf16* __restrict__ Wcat,
              const float* __restrict__ bcat, const int* __restrict__ timei,
              float* __restrict__ out)
{
    const int t = threadIdx.x, w = t >> 6, lane = t & 63;
    const int l16 = lane & 15, quad = lane >> 4;
    const int r0 = blockIdx.x * 64 + w * 16;
    const short* xp = (const short*)x + (size_t)(r0 + l16) * Dn + quad * 8;
    const short* wp = (const short*)Wcat + (size_t)l16 * Dn + quad * 8;

    f32x4 acc[2] = {};
    #pragma unroll
    for (int kk = 0; kk < 16; ++kk) {
        short8 af = *(const short8*)(xp + kk * 32);
        short8 b0 = *(const short8*)(wp + kk * 32);
        short8 b1 = *(const short8*)(wp + 16 * Dn + kk * 32);
        acc[0] = __builtin_amdgcn_mfma_f32_16x16x32_bf16(af, b0, acc[0], 0, 0, 0);
        acc[1] = __builtin_amdgcn_mfma_f32_16x16x32_bf16(af, b1, acc[1], 0, 0, 0);
    }

    #pragma unroll
    for (int nt = 0; nt < 2; ++nt) {
        const int col = nt * 16 + l16;
        const float bb = bcat[col];
        #pragma unroll
        for (int r = 0; r < 4; ++r) {
            const int row = r0 + quad * 4 + r;
            float v = acc[nt][r] + bb;
            float sg = 1.f / (1.f + expf(-v));
            if (col < FEATn)
                out[(size_t)row * FEATn + col] = sg;
            else if (col < 2 * FEATn)
                out[(size_t)BSn * FEATn + BSn + (size_t)row * FEATn + (col - FEATn)] = sg;
        }
    }
    if (l16 == 0) {
        #pragma unroll
        for (int r = 0; r < 4; ++r) {
            const int row = r0 + quad * 4 + r;
            out[(size_t)BSn * FEATn + row] = (float)timei[row];
        }
    }
}

// ---------------------------------------------------------------------------
extern "C" void kernel_launch(void* const* d_in, const int* in_sizes, int n_in,
                              void* d_out, int out_size, void* d_ws, size_t ws_size,
                              hipStream_t stream)
{
    const float* tgt    = (const float*)d_in[0];
    const float* memory = (const float*)d_in[1];
    const int*   timei  = (const int*)  d_in[2];
    const int*   gender = (const int*)  d_in[3];
    const int*   race   = (const int*)  d_in[4];
    const float* maskp  = (const float*)d_in[5];
    const float* w_f2h  = (const float*)d_in[6];
    const float* b_f2h  = (const float*)d_in[7];
    const float* emb_t  = (const float*)d_in[8];
    const float* emb_g  = (const float*)d_in[9];
    const float* emb_r  = (const float*)d_in[10];
    const float* wq1 = (const float*)d_in[11]; const float* bq1 = (const float*)d_in[12];
    const float* wk1 = (const float*)d_in[13]; const float* bk1 = (const float*)d_in[14];
    const float* wv1 = (const float*)d_in[15]; const float* bv1 = (const float*)d_in[16];
    const float* wo1 = (const float*)d_in[17]; const float* bo1 = (const float*)d_in[18];
    const float* g1  = (const float*)d_in[19]; const float* be1 = (const float*)d_in[20];
    const float* wq2 = (const float*)d_in[21]; const float* bq2 = (const float*)d_in[22];
    const float* wk2 = (const float*)d_in[23]; const float* bk2 = (const float*)d_in[24];
    const float* wv2 = (const float*)d_in[25]; const float* bv2 = (const float*)d_in[26];
    const float* wo2 = (const float*)d_in[27]; const float* bo2 = (const float*)d_in[28];
    const float* g2  = (const float*)d_in[29]; const float* be2 = (const float*)d_in[30];
    const float* w1f = (const float*)d_in[31]; const float* b1f = (const float*)d_in[32];
    const float* w2f = (const float*)d_in[33]; const float* b2f = (const float*)d_in[34];
    const float* gfp = (const float*)d_in[35]; const float* bff = (const float*)d_in[36];
    const float* w_out = (const float*)d_in[37]; const float* b_out = (const float*)d_in[38];
    const float* w_m   = (const float*)d_in[39]; const float* b_m   = (const float*)d_in[40];
    float* out = (float*)d_out;

    // ---- workspace layout (bf16 elems) ----
    constexpr size_t WH  = 1572864;            // headed / wo per-array
    constexpr size_t WF  = 6291456;            // w1f / w2f per-array
    constexpr size_t NA  = (size_t)BSn * Dn;   // activation elems
    bf16* wsb   = (bf16*)d_ws;
    bf16* wq1t  = wsb;
    bf16* wk1t  = wq1t + WH;
    bf16* wv1t  = wk1t + WH;
    bf16* wo1t  = wv1t + WH;
    bf16* wq2t  = wo1t + WH;
    bf16* wk2t  = wq2t + WH;
    bf16* wv2t  = wk2t + WH;
    bf16* wo2t  = wv2t + WH;
    bf16* w1ft  = wo2t + WH;
    bf16* w2ft  = w1ft + WF;
    bf16* memb  = w2ft + WF;
    bf16* x     = memb + NA;
    bf16* b1    = x  + NA;
    bf16* b2    = b1 + NA;
    bf16* b3    = b2 + NA;     // Vt [512][8192] from TRANSV v-proj
    bf16* b4    = b3 + NA;
    bf16* h1    = b1;          // [8192][2048] spans b1..b4
    bf16* wcat  = b4 + NA;     // [32][512]
    float* bcat = (float*)(wcat + 32 * Dn);

    dim3 blk(256);

    // ---- weight transpose+convert (batched) ----
    k_tcvt6<<<dim3( 2, 16, 288), blk, 0, stream>>>(
        wq1, wq1t, wk1, wk1t, wv1, wv1t, wq2, wq2t, wk2, wk2t, wv2, wv2t,
        512, 64, 48);
    k_tcvt6<<<dim3(16, 16, 12), blk, 0, stream>>>(
        wo1, wo1t, wo2, wo2t, wo1, wo1t, wo1, wo1t, wo1, wo1t, wo1, wo1t,
        512, 512, 6);
    k_tcvt6<<<dim3(64, 16, 6), blk, 0, stream>>>(
        w1f, w1ft, w1f, w1ft, w1f, w1ft, w1f, w1ft, w1f, w1ft, w1f, w1ft,
        512, 2048, 6);
    k_tcvt6<<<dim3(16, 64, 6), blk, 0, stream>>>(
        w2f, w2ft, w2f, w2ft, w2f, w2ft, w2f, w2ft, w2f, w2ft, w2f, w2ft,
        2048, 512, 6);
    k_cvt <<<dim3(NA / 256), blk, 0, stream>>>(memory, memb);
    k_prep_final<<<dim3(64), blk, 0, stream>>>(w_out, b_out, w_m, b_m, wcat, bcat);

    k_embed<<<dim3((BSn * Dn) / 256), blk, 0, stream>>>(
        tgt, maskp, w_f2h, b_f2h, timei, gender, race, emb_t, emb_g, emb_r, x);

    dim3 gP3(Dn / 128, BSn / 128, 3);   // qkv fused, 128x128: 768 blocks (3/CU)
    dim3 gP6(Dn / 64,  BSn / 64,  1);   // wo / ffn2, 64x64: 1024 blocks (4/CU)
    dim3 gF (Fn / 128, BSn / 128, 1);   // ffn1, 128x128: 1024 blocks (4/CU)
    dim3 gA (Bn * Hn * 4);
    dim3 gL (BSn / 4);
    constexpr size_t WSL = 262144;
    constexpr size_t WFL = 1048576;

    for (int l = 0; l < Ln; ++l) {
        // ---- self-attention ----
        k_gemm_bf<128, 128, false, false, true><<<gP3, blk, 0, stream>>>(
            x, x, x,
            wq1t + l * WSL, wk1t + l * WSL, wv1t + l * WSL,
            bq1 + l * Dn, bk1 + l * Dn, bv1 + l * Dn,
            nullptr, b1, b2, b3, BSn, Dn, Dn);
        k_attn_mfma<<<gA, blk, 0, stream>>>(b1, b2, b3, b4);
        k_gemm_bf<64, 64, false, true><<<gP6, blk, 0, stream>>>(
            b4, b4, b4, wo1t + l * WSL, wo1t + l * WSL, wo1t + l * WSL,
            bo1 + l * Dn, bo1 + l * Dn, bo1 + l * Dn,
            x, x, x, x, BSn, Dn, Dn);
        k_ln<<<gL, blk, 0, stream>>>(x, g1 + l * Dn, be1 + l * Dn, x);
        // ---- cross block: q,k from memory; v from x ----
        k_gemm_bf<128, 128, false, false, true><<<gP3, blk, 0, stream>>>(
            memb, memb, x,
            wq2t + l * WSL, wk2t + l * WSL, wv2t + l * WSL,
            bq2 + l * Dn, bk2 + l * Dn, bv2 + l * Dn,
            nullptr, b1, b2, b3, BSn, Dn, Dn);
        k_attn_mfma<<<gA, blk, 0, stream>>>(b1, b2, b3, b4);
        k_gemm_bf<64, 64, false, true><<<gP6, blk, 0, stream>>>(
            b4, b4, b4, wo2t + l * WSL, wo2t + l * WSL, wo2t + l * WSL,
            bo2 + l * Dn, bo2 + l * Dn, bo2 + l * Dn,
            x, x, x, x, BSn, Dn, Dn);
        k_ln<<<gL, blk, 0, stream>>>(x, g2 + l * Dn, be2 + l * Dn, x);
        // ---- feed-forward ----
        k_gemm_bf<128, 128, true, false><<<gF, blk, 0, stream>>>(
            x, x, x, w1ft + l * WFL, w1ft + l * WFL, w1ft + l * WFL,
            b1f + l * Fn, b1f + l * Fn, b1f + l * Fn,
            nullptr, h1, h1, h1, BSn, Fn, Dn);
        k_gemm_bf<64, 64, false, true><<<gP6, blk, 0, stream>>>(
            h1, h1, h1, w2ft + l * WFL, w2ft + l * WFL, w2ft + l * WFL,
            b2f + l * Dn, b2f + l * Dn, b2f + l * Dn,
            x, x, x, x, BSn, Dn, Fn);
        k_ln<<<gL, blk, 0, stream>>>(x, gfp + l * Dn, bff + l * Dn, x);
    }

    k_final2<<<dim3(BSn / 64), blk, 0, stream>>>(x, wcat, bcat, timei, out);
}

// Round 7
// 1590.447 us; speedup vs baseline: 1.0751x; 1.0751x over previous
//
#include <hip/hip_runtime.h>
#include <hip/hip_bf16.h>
#include <math.h>

// Problem constants
constexpr int Bn   = 32;
constexpr int Sn   = 256;
constexpr int Dn   = 512;
constexpr int Hn   = 8;
constexpr int DKn  = 64;
constexpr int Fn   = 2048;
constexpr int Ln   = 6;
constexpr int FEATn= 9;
constexpr int BSn  = Bn * Sn;          // 8192 rows

typedef __hip_bfloat16 bf16;
typedef __attribute__((ext_vector_type(8))) short short8;
typedef __attribute__((ext_vector_type(4))) short short4v;
typedef __attribute__((ext_vector_type(4))) float f32x4;

// global->LDS async copy, 16B per lane, LDS dest = wave-uniform base + lane*16
#define GLOAD_LDS16(gp, lp)                                                   \
    __builtin_amdgcn_global_load_lds(                                         \
        (const __attribute__((address_space(1))) void*)(gp),                  \
        (__attribute__((address_space(3))) void*)(lp), 16, 0, 0)

__device__ __forceinline__ short f2bs(float f) {
    __hip_bfloat16 h = __float2bfloat16(f);
    return *reinterpret_cast<short*>(&h);
}
__device__ __forceinline__ float bs2f(short s) {
    unsigned u = ((unsigned)(unsigned short)s) << 16;
    return *reinterpret_cast<float*>(&u);
}

// ---------------------------------------------------------------------------
// Embedding: x = (tgt*mask)@w_f2h + b_f2h + pos_emb + emb_time/gender/race
// ---------------------------------------------------------------------------
__global__ __launch_bounds__(256)
void k_embed(const float* __restrict__ tgt, const float* __restrict__ mask,
             const float* __restrict__ w_f2h, const float* __restrict__ b_f2h,
             const int* __restrict__ timei, const int* __restrict__ gender,
             const int* __restrict__ race,
             const float* __restrict__ emb_t, const float* __restrict__ emb_g,
             const float* __restrict__ emb_r, bf16* __restrict__ x)
{
    int idx = blockIdx.x * 256 + threadIdx.x;   // over BSn*Dn
    int d  = idx & (Dn - 1);
    int bs = idx >> 9;                           // /Dn
    int b  = bs / Sn;
    int s  = bs & (Sn - 1);
    const float* tg = tgt  + (size_t)bs * FEATn;
    const float* mk = mask + (size_t)bs * FEATn;
    float acc = b_f2h[d];
    #pragma unroll
    for (int f = 0; f < FEATn; ++f) acc += tg[f] * mk[f] * w_f2h[f * Dn + d];
    float phase = (float)s * expf(-((float)d / (float)Dn) * 9.210340372f); // ln(1e4)
    acc += (d & 1) ? cosf(phase) : sinf(phase);
    acc += emb_t[(size_t)timei[bs] * Dn + d];
    acc += emb_g[(size_t)gender[b] * Dn + d];
    acc += emb_r[(size_t)race[b]   * Dn + d];
    x[idx] = __float2bfloat16(acc);
}

// ---------------------------------------------------------------------------
// fp32 -> bf16 elementwise convert
// ---------------------------------------------------------------------------
__global__ __launch_bounds__(256)
void k_cvt(const float* __restrict__ in, bf16* __restrict__ out)
{
    int i = blockIdx.x * 256 + threadIdx.x;
    out[i] = __float2bfloat16(in[i]);
}

// ---------------------------------------------------------------------------
// Transpose + convert: in fp32 [B][R][C] -> out bf16 [B][C][R]
// Batched over up to 6 source/dest pairs: z in [0, 6*ZB); sel = z / ZB.
// ---------------------------------------------------------------------------
__global__ __launch_bounds__(256)
void k_tcvt6(const float* __restrict__ i0, bf16* __restrict__ o0,
             const float* __restrict__ i1, bf16* __restrict__ o1,
             const float* __restrict__ i2, bf16* __restrict__ o2,
             const float* __restrict__ i3, bf16* __restrict__ o3,
             const float* __restrict__ i4, bf16* __restrict__ o4,
             const float* __restrict__ i5, bf16* __restrict__ o5,
             int R, int C, int ZB)
{
    __shared__ float ts[32][33];
    const int sel = blockIdx.z / ZB, zi = blockIdx.z % ZB;
    const float* in  = sel == 0 ? i0 : sel == 1 ? i1 : sel == 2 ? i2
                     : sel == 3 ? i3 : sel == 4 ? i4 : i5;
    bf16*        out = sel == 0 ? o0 : sel == 1 ? o1 : sel == 2 ? o2
                     : sel == 3 ? o3 : sel == 4 ? o4 : o5;
    const int t  = threadIdx.x;
    const int tx = t & 31, ty = t >> 5;       // 8 rows per pass
    const int r0 = blockIdx.y * 32, c0 = blockIdx.x * 32;
    const size_t zo = (size_t)zi * R * C;
    #pragma unroll
    for (int i = 0; i < 4; ++i)
        ts[ty + 8 * i][tx] = in[zo + (size_t)(r0 + ty + 8 * i) * C + c0 + tx];
    __syncthreads();
    #pragma unroll
    for (int i = 0; i < 4; ++i)
        out[zo + (size_t)(c0 + ty + 8 * i) * R + r0 + tx] =
            __float2bfloat16(ts[tx][ty + 8 * i]);
}

// ---------------------------------------------------------------------------
// Prep for k_final2: Wcat bf16 [32][512] = concat(w_out^T, w_m^T, zero-pad),
// bcat fp32 [32] = concat(b_out, b_m, 0)
// ---------------------------------------------------------------------------
__global__ __launch_bounds__(256)
void k_prep_final(const float* __restrict__ w_out, const float* __restrict__ b_out,
                  const float* __restrict__ w_m, const float* __restrict__ b_m,
                  bf16* __restrict__ Wcat, float* __restrict__ bcat)
{
    int idx = blockIdx.x * 256 + threadIdx.x;   // 32*512
    int n = idx >> 9, k = idx & 511;
    float v = 0.f;
    if (n < FEATn)          v = w_out[(size_t)k * FEATn + n];
    else if (n < 2 * FEATn) v = w_m[(size_t)k * FEATn + (n - FEATn)];
    Wcat[idx] = __float2bfloat16(v);
    if (idx < 32) {
        float bv = idx < FEATn ? b_out[idx]
                 : (idx < 2 * FEATn ? b_m[idx - FEATn] : 0.f);
        bcat[idx] = bv;
    }
}

// ---------------------------------------------------------------------------
// bf16 MFMA GEMM: C[M,N] = A[M,K] @ Bt[N,K]^T + bias (+R)(ReLU)
// Tile BM x BN, BK=32, 4 waves 2x2, LDS-staged coalesced epilogue.
// 1D grid with XCD-locality swizzle (id%8 = XCD slot, round-robin heuristic):
//   stat==0 (A-stationary): XCD owns contiguous m-range, iterates n (then z)
//     inside -> A-tile fetched into that XCD's L2 once (was: 8 n-tiles of one
//     m-tile dispatched consecutively -> 8 XCDs -> 8x A fills; ffn2 showed
//     FETCH 136 MB vs 34 MB unique).
//   stat==1 (W-stationary, for ffn1 where W=8MB > 4MB L2): XCD owns n-range
//     (1 MB of W resident), streams all m-tiles.
// z picks (A,W,bias,C); TRANSV && z==2: operand-swapped MFMA -> writes C^T.
// ---------------------------------------------------------------------------
template<int BM, int BN, bool RELU, bool RESID, bool TRANSV = false>
__global__ __launch_bounds__(256)
void k_gemm_bf(const bf16* __restrict__ A0, const bf16* __restrict__ A1,
               const bf16* __restrict__ A2,
               const bf16* __restrict__ W0, const bf16* __restrict__ W1,
               const bf16* __restrict__ W2,
               const float* __restrict__ bi0, const float* __restrict__ bi1,
               const float* __restrict__ bi2,
               const bf16* __restrict__ R,
               bf16* __restrict__ C0, bf16* __restrict__ C1, bf16* __restrict__ C2,
               int M, int N, int K, int MTt, int NTt, int ZN, int stat)
{
    constexpr int WTM = BM / 2, WTN = BN / 2;     // wave tile
    constexpr int MT  = WTM / 16, NT = WTN / 16;  // MFMA tiles per wave
    constexpr int NCA = BM / 64;                  // A staging calls per wave
    constexpr int NCB = BN / 64;
    constexpr int CSTR   = BN + 8;                // Cs row stride (shorts)
    constexpr int PASSES = BM / 64;               // epilogue row-half passes

    // ---- XCD swizzle decode ----
    const int id = blockIdx.x;
    const int c  = id & 7, j = id >> 3;
    int mt, nt, z;
    if (stat == 0) {
        const int inner = NTt * ZN;
        const int ml = j / inner, r = j - ml * inner;
        mt = c * (MTt >> 3) + ml;
        nt = r % NTt;
        z  = r / NTt;
    } else {
        const int inner = MTt * ZN;
        const int nl = j / inner, r = j - nl * inner;
        nt = c * (NTt >> 3) + nl;
        mt = r % MTt;
        z  = r / MTt;
    }
    const int m0 = mt * BM, n0 = nt * BN;

    const short* A   = (const short*)(z == 0 ? A0 : (z == 1 ? A1 : A2));
    const short* W   = (const short*)(z == 0 ? W0 : (z == 1 ? W1 : W2));
    const float* bia = (z == 0 ? bi0 : (z == 1 ? bi1 : bi2));
    bf16*        C   = (z == 0 ? C0 : (z == 1 ? C1 : C2));

    __shared__ __align__(16) short As[BM * 32];   // [row][k] 64B rows
    __shared__ __align__(16) short Bs[BN * 32];
    __shared__ __align__(16) short Cs[64 * CSTR]; // epilogue staging

    const int t    = threadIdx.x;
    const int w    = t >> 6, lane = t & 63;
    const int l16  = lane & 15, quad = lane >> 4;
    const int wm   = (w & 1) * WTM, wn = (w >> 1) * WTN;

    const short* Agp[NCA];
    const short* Bgp[NCB];
    #pragma unroll
    for (int i = 0; i < NCA; ++i) {
        const int cc = w * BM + i * 64 + lane;
        Agp[i] = A + (size_t)(m0 + (cc >> 2)) * K + (cc & 3) * 8;
    }
    #pragma unroll
    for (int i = 0; i < NCB; ++i) {
        const int cc = w * BN + i * 64 + lane;
        Bgp[i] = W + (size_t)(n0 + (cc >> 2)) * K + (cc & 3) * 8;
    }

    f32x4 acc[MT][NT] = {};
    const bool tv = TRANSV && (z == 2);

    for (int k0 = 0; k0 < K; k0 += 32) {
        #pragma unroll
        for (int i = 0; i < NCA; ++i) {
            GLOAD_LDS16(Agp[i], As + (w * BM + i * 64) * 8);
            Agp[i] += 32;
        }
        #pragma unroll
        for (int i = 0; i < NCB; ++i) {
            GLOAD_LDS16(Bgp[i], Bs + (w * BN + i * 64) * 8);
            Bgp[i] += 32;
        }
        __syncthreads();

        short8 af[MT], bf[NT];
        #pragma unroll
        for (int mi = 0; mi < MT; ++mi)
            af[mi] = *(const short8*)(As + (wm + mi * 16 + l16) * 32 + quad * 8);
        #pragma unroll
        for (int ni = 0; ni < NT; ++ni)
            bf[ni] = *(const short8*)(Bs + (wn + ni * 16 + l16) * 32 + quad * 8);
        if (tv) {
            #pragma unroll
            for (int mi = 0; mi < MT; ++mi)
                #pragma unroll
                for (int ni = 0; ni < NT; ++ni)
                    acc[mi][ni] = __builtin_amdgcn_mfma_f32_16x16x32_bf16(
                        bf[ni], af[mi], acc[mi][ni], 0, 0, 0);
        } else {
            #pragma unroll
            for (int mi = 0; mi < MT; ++mi)
                #pragma unroll
                for (int ni = 0; ni < NT; ++ni)
                    acc[mi][ni] = __builtin_amdgcn_mfma_f32_16x16x32_bf16(
                        af[mi], bf[ni], acc[mi][ni], 0, 0, 0);
        }
        __syncthreads();
    }

    if (tv) {
        // D[m = W-row (wn side)][n = token (wm side)]; output C^T [N][M].
        constexpr int CPR = BM / 8;
        #pragma unroll
        for (int p = 0; p < PASSES; ++p) {
            if (PASSES == 1 || wn == p * 64) {
                #pragma unroll
                for (int ni = 0; ni < NT; ++ni) {
                    #pragma unroll
                    for (int r = 0; r < 4; ++r) {
                        const int lrow = wn - p * 64 + ni * 16 + quad * 4 + r;
                        const float bb = bia[n0 + p * 64 + lrow];
                        #pragma unroll
                        for (int mi = 0; mi < MT; ++mi)
                            Cs[lrow * CSTR + wm + mi * 16 + l16] =
                                f2bs(acc[mi][ni][r] + bb);
                    }
                }
            }
            __syncthreads();
            #pragma unroll
            for (int cc = 0; cc < 64 * CPR; cc += 256) {
                const int row = (cc + t) / CPR, colc = (cc + t) % CPR;
                short8 cv = *(const short8*)(Cs + row * CSTR + colc * 8);
                *(short8*)((short*)C + (size_t)(n0 + p * 64 + row) * M
                                      + m0 + colc * 8) = cv;
            }
            __syncthreads();
        }
    } else {
        constexpr int CPR = BN / 8;
        #pragma unroll
        for (int p = 0; p < PASSES; ++p) {
            if (PASSES == 1 || wm == p * 64) {
                #pragma unroll
                for (int ni = 0; ni < NT; ++ni) {
                    const float bb = bia[n0 + wn + ni * 16 + l16];
                    #pragma unroll
                    for (int mi = 0; mi < MT; ++mi) {
                        const int lrow0 = wm - p * 64 + mi * 16 + quad * 4;
                        #pragma unroll
                        for (int r = 0; r < 4; ++r) {
                            float v = acc[mi][ni][r] + bb;
                            if (RELU) v = fmaxf(v, 0.f);
                            Cs[(lrow0 + r) * CSTR + wn + ni * 16 + l16] = f2bs(v);
                        }
                    }
                }
            }
            __syncthreads();
            #pragma unroll
            for (int cc = 0; cc < 64 * CPR; cc += 256) {
                const int row = (cc + t) / CPR, colc = (cc + t) % CPR;
                const size_t goff = (size_t)(m0 + p * 64 + row) * N + n0 + colc * 8;
                short8 cv = *(const short8*)(Cs + row * CSTR + colc * 8);
                if (RESID) {
                    short8 rv = *(const short8*)((const short*)R + goff);
                    short8 ov;
                    #pragma unroll
                    for (int i = 0; i < 8; ++i)
                        ov[i] = f2bs(bs2f(cv[i]) + bs2f(rv[i]));
                    *(short8*)((short*)C + goff) = ov;
                } else {
                    *(short8*)((short*)C + goff) = cv;
                }
            }
            __syncthreads();
        }
    }
}

// ---------------------------------------------------------------------------
// MFMA attention. q,k in [B,S,H*DK]; vT in [H*DK][B*S]; out in [B,S,H*DK].
// Block = (b,h,64-query tile), 4 waves x (16q x 256k).
// Block id: qt slowest (stride 256 = same XCD slot) so the 4 q-tiles sharing
// one (b,h)'s K/V hit the same L2.
// ---------------------------------------------------------------------------
__global__ __launch_bounds__(256)
void k_attn_mfma(const bf16* __restrict__ q, const bf16* __restrict__ k,
                 const bf16* __restrict__ vT, bf16* __restrict__ ocat)
{
    __shared__ __align__(16) short smem[33280];      // 66560 B
    short* Vst = smem;            // [64 dv][256 key], 16B chunks XOR-swizzled
    short* Ks  = smem + 16384;    // [256 key][64 dk], 16B chunks XOR-swizzled
    short* Ps  = smem + 16384;    // [64 q][264] bf16, overlays Ks (after barrier)
    short* Cs  = smem + 16384;    // [64 q][72] epilogue staging (after barrier)

    const int t = threadIdx.x, w = t >> 6, lane = t & 63;
    const int l16 = lane & 15, quad = lane >> 4;
    const int qt = blockIdx.x >> 8;
    const int bh = blockIdx.x & 255;
    const int h  = bh & 7;
    const int b  = bh >> 3;
    const int q0 = qt * 64;

    const short* kg = (const short*)k  + (size_t)b * Sn * Dn + h * DKn;
    const short* qg = (const short*)q  + (size_t)b * Sn * Dn + h * DKn;
    const short* vg = (const short*)vT + (size_t)h * DKn * BSn + b * Sn;

    #pragma unroll
    for (int i = 0; i < 8; ++i) {
        const int c   = w * 512 + i * 64 + lane;
        const int key = c >> 3, cgk = (c & 7) ^ (key & 7);
        GLOAD_LDS16(kg + (size_t)key * Dn + cgk * 8, Ks + (w * 512 + i * 64) * 8);
        const int dv = c >> 5, cgv = (c & 31) ^ (dv & 7);
        GLOAD_LDS16(vg + (size_t)dv * BSn + cgv * 8, Vst + (w * 512 + i * 64) * 8);
    }

    const short* qp = qg + (size_t)(q0 + w * 16 + l16) * Dn + quad * 8;
    short8 bq0 = *(const short8*)(qp);
    short8 bq1 = *(const short8*)(qp + 32);
    __syncthreads();

    // ---- S^T = K @ Q^T ----
    f32x4 accs[16];
    #pragma unroll
    for (int mi = 0; mi < 16; ++mi) accs[mi] = f32x4{0.f, 0.f, 0.f, 0.f};
    #pragma unroll
    for (int mi = 0; mi < 16; ++mi) {
        const int key = mi * 16 + l16;
        const int r0s = (quad     ^ (key & 7)) * 8;
        const int r1s = ((quad+4) ^ (key & 7)) * 8;
        short8 af0 = *(const short8*)(Ks + key * 64 + r0s);
        short8 af1 = *(const short8*)(Ks + key * 64 + r1s);
        accs[mi] = __builtin_amdgcn_mfma_f32_16x16x32_bf16(af0, bq0, accs[mi], 0, 0, 0);
        accs[mi] = __builtin_amdgcn_mfma_f32_16x16x32_bf16(af1, bq1, accs[mi], 0, 0, 0);
    }

    // ---- softmax over keys ----
    float mx = -1e30f;
    #pragma unroll
    for (int mi = 0; mi < 16; ++mi)
        #pragma unroll
        for (int r = 0; r < 4; ++r) mx = fmaxf(mx, accs[mi][r]);
    mx = fmaxf(mx, __shfl_xor(mx, 16));
    mx = fmaxf(mx, __shfl_xor(mx, 32));
    float sum = 0.f;
    #pragma unroll
    for (int mi = 0; mi < 16; ++mi)
        #pragma unroll
        for (int r = 0; r < 4; ++r) {
            float e = __expf((accs[mi][r] - mx) * 0.125f);
            accs[mi][r] = e;
            sum += e;
        }
    sum += __shfl_xor(sum, 16);
    sum += __shfl_xor(sum, 32);
    const float rs = 1.f / sum;

    __syncthreads();

    short* pr = Ps + (w * 16 + l16) * 264;
    #pragma unroll
    for (int mi = 0; mi < 16; ++mi) {
        short4v pk;
        pk.x = f2bs(accs[mi][0] * rs);
        pk.y = f2bs(accs[mi][1] * rs);
        pk.z = f2bs(accs[mi][2] * rs);
        pk.w = f2bs(accs[mi][3] * rs);
        *(short4v*)(pr + mi * 16 + quad * 4) = pk;
    }
    __syncthreads();

    // ---- O = P @ V ----
    f32x4 acco[4];
    #pragma unroll
    for (int nt = 0; nt < 4; ++nt) acco[nt] = f32x4{0.f, 0.f, 0.f, 0.f};
    #pragma unroll
    for (int k0 = 0; k0 < 8; ++k0) {
        short8 pa = *(const short8*)(pr + k0 * 32 + quad * 8);
        #pragma unroll
        for (int nt = 0; nt < 4; ++nt) {
            const int dv = nt * 16 + l16;
            const int sl = ((4 * k0 + quad) ^ (dv & 7)) * 8;
            short8 vb = *(const short8*)(Vst + dv * 256 + sl);
            acco[nt] = __builtin_amdgcn_mfma_f32_16x16x32_bf16(pa, vb, acco[nt], 0, 0, 0);
        }
    }
    __syncthreads();   // P reads done before Cs overlays Ps

    // ---- epilogue via LDS -> coalesced b128 stores ----
    #pragma unroll
    for (int nt = 0; nt < 4; ++nt)
        #pragma unroll
        for (int r = 0; r < 4; ++r)
            Cs[(w * 16 + quad * 4 + r) * 72 + nt * 16 + l16] = f2bs(acco[nt][r]);
    __syncthreads();
    #pragma unroll
    for (int c = 0; c < 512; c += 256) {
        const int row = (c + t) >> 3, colc = (c + t) & 7;
        short8 cv = *(const short8*)(Cs + row * 72 + colc * 8);
        *(short8*)((short*)ocat + (size_t)(b * Sn + q0 + row) * Dn
                                 + h * DKn + colc * 8) = cv;
    }
}

// ---------------------------------------------------------------------------
// LayerNorm over D=512: one wave per row, b128 loads, shfl-only reduction.
// ---------------------------------------------------------------------------
__global__ __launch_bounds__(256)
void k_ln(const bf16* __restrict__ y, const float* __restrict__ g,
          const float* __restrict__ be, bf16* __restrict__ xo)
{
    const int t = threadIdx.x, w = t >> 6, lane = t & 63;
    const int row = blockIdx.x * 4 + w;
    const short* yr = (const short*)y + (size_t)row * Dn + lane * 8;
    short8 v8 = *(const short8*)yr;
    float f[8];
    float s1 = 0.f, s2 = 0.f;
    #pragma unroll
    for (int i = 0; i < 8; ++i) {
        f[i] = bs2f(v8[i]);
        s1 += f[i];
        s2 += f[i] * f[i];
    }
    #pragma unroll
    for (int off = 1; off < 64; off <<= 1) {
        s1 += __shfl_xor(s1, off);
        s2 += __shfl_xor(s2, off);
    }
    const float mean = s1 * (1.f / Dn);
    const float var  = s2 * (1.f / Dn) - mean * mean;
    const float isd  = rsqrtf(var + 1e-5f);
    const float4 g0 = *(const float4*)(g  + lane * 8);
    const float4 g1 = *(const float4*)(g  + lane * 8 + 4);
    const float4 b0 = *(const float4*)(be + lane * 8);
    const float4 b1 = *(const float4*)(be + lane * 8 + 4);
    const float gg[8] = {g0.x, g0.y, g0.z, g0.w, g1.x, g1.y, g1.z, g1.w};
    const float bb[8] = {b0.x, b0.y, b0.z, b0.w, b1.x, b1.y, b1.z, b1.w};
    short8 o8;
    #pragma unroll
    for (int i = 0; i < 8; ++i)
        o8[i] = f2bs((f[i] - mean) * isd * gg[i] + bb[i]);
    *(short8*)((short*)xo + (size_t)row * Dn + lane * 8) = o8;
}

// ---------------------------------------------------------------------------
// Final head as skinny MFMA GEMM: out = sigmoid(X @ Wcat^T + bcat).
// ---------------------------------------------------------------------------
__global__ __launch_bounds__(256)
void k_final2(const bf16* __restrict__ x, const bf16* __restrict__ Wcat,
              const float* __restrict__ bcat, const int* __restrict__ timei,
              float* __restrict__ out)
{
    const int t = threadIdx.x, w = t >> 6, lane = t & 63;
    const int l16 = lane & 15, quad = lane >> 4;
    const int r0 = blockIdx.x * 64 + w * 16;
    const short* xp = (const short*)x + (size_t)(r0 + l16) * Dn + quad * 8;
    const short* wp = (const short*)Wcat + (size_t)l16 * Dn + quad * 8;

    f32x4 acc[2] = {};
    #pragma unroll
    for (int kk = 0; kk < 16; ++kk) {
        short8 af = *(const short8*)(xp + kk * 32);
        short8 b0 = *(const short8*)(wp + kk * 32);
        short8 b1 = *(const short8*)(wp + 16 * Dn + kk * 32);
        acc[0] = __builtin_amdgcn_mfma_f32_16x16x32_bf16(af, b0, acc[0], 0, 0, 0);
        acc[1] = __builtin_amdgcn_mfma_f32_16x16x32_bf16(af, b1, acc[1], 0, 0, 0);
    }

    #pragma unroll
    for (int nt = 0; nt < 2; ++nt) {
        const int col = nt * 16 + l16;
        const float bb = bcat[col];
        #pragma unroll
        for (int r = 0; r < 4; ++r) {
            const int row = r0 + quad * 4 + r;
            float v = acc[nt][r] + bb;
            float sg = 1.f / (1.f + expf(-v));
            if (col < FEATn)
                out[(size_t)row * FEATn + col] = sg;
            else if (col < 2 * FEATn)
                out[(size_t)BSn * FEATn + BSn + (size_t)row * FEATn + (col - FEATn)] = sg;
        }
    }
    if (l16 == 0) {
        #pragma unroll
        for (int r = 0; r < 4; ++r) {
            const int row = r0 + quad * 4 + r;
            out[(size_t)BSn * FEATn + row] = (float)timei[row];
        }
    }
}

// ---------------------------------------------------------------------------
extern "C" void kernel_launch(void* const* d_in, const int* in_sizes, int n_in,
                              void* d_out, int out_size, void* d_ws, size_t ws_size,
                              hipStream_t stream)
{
    const float* tgt    = (const float*)d_in[0];
    const float* memory = (const float*)d_in[1];
    const int*   timei  = (const int*)  d_in[2];
    const int*   gender = (const int*)  d_in[3];
    const int*   race   = (const int*)  d_in[4];
    const float* maskp  = (const float*)d_in[5];
    const float* w_f2h  = (const float*)d_in[6];
    const float* b_f2h  = (const float*)d_in[7];
    const float* emb_t  = (const float*)d_in[8];
    const float* emb_g  = (const float*)d_in[9];
    const float* emb_r  = (const float*)d_in[10];
    const float* wq1 = (const float*)d_in[11]; const float* bq1 = (const float*)d_in[12];
    const float* wk1 = (const float*)d_in[13]; const float* bk1 = (const float*)d_in[14];
    const float* wv1 = (const float*)d_in[15]; const float* bv1 = (const float*)d_in[16];
    const float* wo1 = (const float*)d_in[17]; const float* bo1 = (const float*)d_in[18];
    const float* g1  = (const float*)d_in[19]; const float* be1 = (const float*)d_in[20];
    const float* wq2 = (const float*)d_in[21]; const float* bq2 = (const float*)d_in[22];
    const float* wk2 = (const float*)d_in[23]; const float* bk2 = (const float*)d_in[24];
    const float* wv2 = (const float*)d_in[25]; const float* bv2 = (const float*)d_in[26];
    const float* wo2 = (const float*)d_in[27]; const float* bo2 = (const float*)d_in[28];
    const float* g2  = (const float*)d_in[29]; const float* be2 = (const float*)d_in[30];
    const float* w1f = (const float*)d_in[31]; const float* b1f = (const float*)d_in[32];
    const float* w2f = (const float*)d_in[33]; const float* b2f = (const float*)d_in[34];
    const float* gfp = (const float*)d_in[35]; const float* bff = (const float*)d_in[36];
    const float* w_out = (const float*)d_in[37]; const float* b_out = (const float*)d_in[38];
    const float* w_m   = (const float*)d_in[39]; const float* b_m   = (const float*)d_in[40];
    float* out = (float*)d_out;

    // ---- workspace layout (bf16 elems) ----
    constexpr size_t WH  = 1572864;            // headed / wo per-array
    constexpr size_t WF  = 6291456;            // w1f / w2f per-array
    constexpr size_t NA  = (size_t)BSn * Dn;   // activation elems
    bf16* wsb   = (bf16*)d_ws;
    bf16* wq1t  = wsb;
    bf16* wk1t  = wq1t + WH;
    bf16* wv1t  = wk1t + WH;
    bf16* wo1t  = wv1t + WH;
    bf16* wq2t  = wo1t + WH;
    bf16* wk2t  = wq2t + WH;
    bf16* wv2t  = wk2t + WH;
    bf16* wo2t  = wv2t + WH;
    bf16* w1ft  = wo2t + WH;
    bf16* w2ft  = w1ft + WF;
    bf16* memb  = w2ft + WF;
    bf16* x     = memb + NA;
    bf16* b1    = x  + NA;
    bf16* b2    = b1 + NA;
    bf16* b3    = b2 + NA;     // Vt [512][8192] from TRANSV v-proj
    bf16* b4    = b3 + NA;
    bf16* h1    = b1;          // [8192][2048] spans b1..b4
    bf16* wcat  = b4 + NA;     // [32][512]
    float* bcat = (float*)(wcat + 32 * Dn);

    dim3 blk(256);

    // ---- weight transpose+convert (batched) ----
    k_tcvt6<<<dim3( 2, 16, 288), blk, 0, stream>>>(
        wq1, wq1t, wk1, wk1t, wv1, wv1t, wq2, wq2t, wk2, wk2t, wv2, wv2t,
        512, 64, 48);
    k_tcvt6<<<dim3(16, 16, 12), blk, 0, stream>>>(
        wo1, wo1t, wo2, wo2t, wo1, wo1t, wo1, wo1t, wo1, wo1t, wo1, wo1t,
        512, 512, 6);
    k_tcvt6<<<dim3(64, 16, 6), blk, 0, stream>>>(
        w1f, w1ft, w1f, w1ft, w1f, w1ft, w1f, w1ft, w1f, w1ft, w1f, w1ft,
        512, 2048, 6);
    k_tcvt6<<<dim3(16, 64, 6), blk, 0, stream>>>(
        w2f, w2ft, w2f, w2ft, w2f, w2ft, w2f, w2ft, w2f, w2ft, w2f, w2ft,
        2048, 512, 6);
    k_cvt <<<dim3(NA / 256), blk, 0, stream>>>(memory, memb);
    k_prep_final<<<dim3(64), blk, 0, stream>>>(w_out, b_out, w_m, b_m, wcat, bcat);

    k_embed<<<dim3((BSn * Dn) / 256), blk, 0, stream>>>(
        tgt, maskp, w_f2h, b_f2h, timei, gender, race, emb_t, emb_g, emb_r, x);

    // 1D swizzled grids: total = MT*NT*ZN
    dim3 gP3(64 * 4 * 3);     // qkv fused 128x128: MT=64, NT=4, Z=3 (A-stationary)
    dim3 gP6(128 * 8);        // wo / ffn2 64x64: MT=128, NT=8 (A-stationary)
    dim3 gF (64 * 16);        // ffn1 128x128: MT=64, NT=16 (W-stationary)
    dim3 gA (Bn * Hn * 4);
    dim3 gL (BSn / 4);
    constexpr size_t WSL = 262144;
    constexpr size_t WFL = 1048576;

    for (int l = 0; l < Ln; ++l) {
        // ---- self-attention ----
        k_gemm_bf<128, 128, false, false, true><<<gP3, blk, 0, stream>>>(
            x, x, x,
            wq1t + l * WSL, wk1t + l * WSL, wv1t + l * WSL,
            bq1 + l * Dn, bk1 + l * Dn, bv1 + l * Dn,
            nullptr, b1, b2, b3, BSn, Dn, Dn, 64, 4, 3, 0);
        k_attn_mfma<<<gA, blk, 0, stream>>>(b1, b2, b3, b4);
        k_gemm_bf<64, 64, false, true><<<gP6, blk, 0, stream>>>(
            b4, b4, b4, wo1t + l * WSL, wo1t + l * WSL, wo1t + l * WSL,
            bo1 + l * Dn, bo1 + l * Dn, bo1 + l * Dn,
            x, x, x, x, BSn, Dn, Dn, 128, 8, 1, 0);
        k_ln<<<gL, blk, 0, stream>>>(x, g1 + l * Dn, be1 + l * Dn, x);
        // ---- cross block: q,k from memory; v from x ----
        k_gemm_bf<128, 128, false, false, true><<<gP3, blk, 0, stream>>>(
            memb, memb, x,
            wq2t + l * WSL, wk2t + l * WSL, wv2t + l * WSL,
            bq2 + l * Dn, bk2 + l * Dn, bv2 + l * Dn,
            nullptr, b1, b2, b3, BSn, Dn, Dn, 64, 4, 3, 0);
        k_attn_mfma<<<gA, blk, 0, stream>>>(b1, b2, b3, b4);
        k_gemm_bf<64, 64, false, true><<<gP6, blk, 0, stream>>>(
            b4, b4, b4, wo2t + l * WSL, wo2t + l * WSL, wo2t + l * WSL,
            bo2 + l * Dn, bo2 + l * Dn, bo2 + l * Dn,
            x, x, x, x, BSn, Dn, Dn, 128, 8, 1, 0);
        k_ln<<<gL, blk, 0, stream>>>(x, g2 + l * Dn, be2 + l * Dn, x);
        // ---- feed-forward ----
        k_gemm_bf<128, 128, true, false><<<gF, blk, 0, stream>>>(
            x, x, x, w1ft + l * WFL, w1ft + l * WFL, w1ft + l * WFL,
            b1f + l * Fn, b1f + l * Fn, b1f + l * Fn,
            nullptr, h1, h1, h1, BSn, Fn, Dn, 64, 16, 1, 1);
        k_gemm_bf<64, 64, false, true><<<gP6, blk, 0, stream>>>(
            h1, h1, h1, w2ft + l * WFL, w2ft + l * WFL, w2ft + l * WFL,
            b2f + l * Dn, b2f + l * Dn, b2f + l * Dn,
            x, x, x, x, BSn, Dn, Fn, 128, 8, 1, 0);
        k_ln<<<gL, blk, 0, stream>>>(x, gfp + l * Dn, bff + l * Dn, x);
    }

    k_final2<<<dim3(BSn / 64), blk, 0, stream>>>(x, wcat, bcat, timei, out);
}